// Round 6
// baseline (382.455 us; speedup 1.0000x reference)
//
#include <hip/hip_runtime.h>
#include <hip/hip_bf16.h>
#include <stdint.h>

typedef __bf16 bf16_t;
typedef __attribute__((ext_vector_type(8))) __bf16 bf16x8;
typedef __attribute__((ext_vector_type(4))) float f32x4;
typedef __attribute__((ext_vector_type(8))) unsigned short u16x8;

#define S_LEN 2048
#define DIM   4096
#define QKVN  6144
#define NHEAD 32
#define HDIM  128

typedef __attribute__((address_space(1))) unsigned int as1_u32;
typedef __attribute__((address_space(3))) unsigned int as3_u32;

__device__ __forceinline__ unsigned short f2bf(float f) {
  unsigned u = __builtin_bit_cast(unsigned, f);
  u += 0x7fffu + ((u >> 16) & 1u);
  return (unsigned short)(u >> 16);
}

__device__ __forceinline__ void gload_lds16(const void* g, void* l) {
  __builtin_amdgcn_global_load_lds(
      (as1_u32*)(unsigned long long)(uintptr_t)g,
      (as3_u32*)(unsigned int)(uintptr_t)l,
      16, 0, 0);
}

__global__ __launch_bounds__(256) void cvt_kernel(const float* __restrict__ in,
                                                  unsigned short* __restrict__ out,
                                                  int n4) {
  int idx = blockIdx.x * 256 + threadIdx.x;
  int stride = gridDim.x * 256;
  for (int i = idx; i < n4; i += stride) {
    float4 v = ((const float4*)in)[i];
    ushort4 o;
    o.x = f2bf(v.x); o.y = f2bf(v.y); o.z = f2bf(v.z); o.w = f2bf(v.w);
    ((ushort4*)out)[i] = o;
  }
}

// ------ 256x128 pipelined GEMM, BK=32, 8 waves (4M x 2N), 512 threads -----
// C(M,N) = A(M,K) * B(N,K)^T. LDS = 2 slots x (A 256x32 + B 128x32) = 48KB.
// 3-deep ledger: body(t) = { ds_read frags(t+1) | MFMA(t) overlaps | lgkm(0);
// barrier; stage(t+3) -> slot just read; vmcnt(3) [t+2 landed, t+3 in
// flight]; barrier }. Swizzle key (row>>1)&3 both sides (R4: conflicts=0).
__device__ __forceinline__ bf16x8 frag_ld(const char* base, int row, int lg) {
  return *(const bf16x8*)(base + row * 64 + ((lg ^ ((row >> 1) & 3)) << 4));
}

__device__ __forceinline__ void load_frags(const char* slot, int wm, int wn,
                                           int lg, int lr, bf16x8* af, bf16x8* bf) {
#pragma unroll
  for (int i = 0; i < 4; ++i) af[i] = frag_ld(slot, wm * 64 + i * 16 + lr, lg);
#pragma unroll
  for (int i = 0; i < 4; ++i)
    bf[i] = frag_ld(slot + 16384, wn * 64 + i * 16 + lr, lg);
}

// 3 loads/thread: A rows tid>>2 and 128+(tid>>2), B row tid>>2.
// Swizzle key identical for row and row+128 ((row>>1)&3 unchanged mod 64).
__device__ __forceinline__ void stage_slot(const bf16_t* a0, const bf16_t* b0,
                                           long ldk128, int k0, char* slot, int tid) {
  gload_lds16(a0 + k0,          slot + tid * 16);
  gload_lds16(a0 + ldk128 + k0, slot + 8192 + tid * 16);
  gload_lds16(b0 + k0,          slot + 16384 + tid * 16);
}

__device__ __forceinline__ void mfma16(const bf16x8* af, const bf16x8* bf,
                                       f32x4 (*acc)[4]) {
#pragma unroll
  for (int mf = 0; mf < 4; ++mf)
#pragma unroll
    for (int nf = 0; nf < 4; ++nf)
      acc[mf][nf] = __builtin_amdgcn_mfma_f32_16x16x32_bf16(af[mf], bf[nf],
                                                            acc[mf][nf], 0, 0, 0);
}

template <int OUTF32>
__global__ __launch_bounds__(512, 2) void gemm_pipe(const bf16_t* __restrict__ A,
                                                    const bf16_t* __restrict__ B,
                                                    void* __restrict__ Cout,
                                                    int M, int N, int K, int nxt) {
  __shared__ char lds[49152];
  const int tid = threadIdx.x;
  const int lane = tid & 63, w = tid >> 6;
  const int wm = w >> 1, wn = w & 1;     // 4 M-waves x 2 N-waves, 64x64 each
  const int lg = lane >> 4, lr = lane & 15;
  const int nwg = gridDim.x;
  const int orig = blockIdx.x;
  const int wgid = (orig & 7) * (nwg >> 3) + (orig >> 3);  // nwg % 8 == 0
  const int bx = wgid % nxt, by = wgid / nxt;
  const long rowA = (long)by * 256;
  const long rowB = (long)bx * 128;

  f32x4 acc[4][4];
  const f32x4 z4 = {0.f, 0.f, 0.f, 0.f};
#pragma unroll
  for (int i = 0; i < 4; ++i)
#pragma unroll
    for (int j = 0; j < 4; ++j) acc[i][j] = z4;

  const int srow = tid >> 2, s4 = tid & 3;
  const long ldk128 = (long)128 * K;
  const bf16_t* Asrc = A + (rowA + srow) * (long)K + ((s4 ^ ((srow >> 1) & 3)) << 3);
  const bf16_t* Bsrc = B + (rowB + srow) * (long)K + ((s4 ^ ((srow >> 1) & 3)) << 3);

  char* s0 = lds;            // tiles of even index
  char* s1 = lds + 24576;    // tiles of odd index
  const int nt = K >> 5;     // even, >= 4

  bf16x8 afA[4], bfA[4], afB[4], bfB[4];

  // prologue: stage tiles 0,1; read frags(0); stage tile 2; tile1 landed
  stage_slot(Asrc, Bsrc, ldk128, 0,  s0, tid);
  stage_slot(Asrc, Bsrc, ldk128, 32, s1, tid);
  asm volatile("s_waitcnt vmcnt(3)" ::: "memory");   // tile0 landed
  __builtin_amdgcn_s_barrier();
  load_frags(s0, wm, wn, lg, lr, afA, bfA);
  asm volatile("s_waitcnt lgkmcnt(0)" ::: "memory");
  __builtin_amdgcn_sched_barrier(0);
  __builtin_amdgcn_s_barrier();                      // all waves read tile0
  stage_slot(Asrc, Bsrc, ldk128, 64, s0, tid);       // tile2 -> s0
  asm volatile("s_waitcnt vmcnt(3)" ::: "memory");   // tile1 landed
  __builtin_amdgcn_s_barrier();

  // body(T): frags(T) in regs, tile T+1 landed, stage(T+2) in flight.
#define GSTEP(T, afC, bfC, afN, bfN, SLOT)                                   \
  {                                                                          \
    load_frags(SLOT, wm, wn, lg, lr, afN, bfN);                              \
    __builtin_amdgcn_sched_barrier(0);                                       \
    __builtin_amdgcn_s_setprio(1);                                           \
    mfma16(afC, bfC, acc);                                                   \
    __builtin_amdgcn_s_setprio(0);                                           \
    asm volatile("s_waitcnt lgkmcnt(0)" ::: "memory");                       \
    __builtin_amdgcn_sched_barrier(0);                                       \
    __builtin_amdgcn_s_barrier();                                            \
    if ((T) + 3 < nt) {                                                      \
      stage_slot(Asrc, Bsrc, ldk128, ((T) + 3) * 32, SLOT, tid);             \
      asm volatile("s_waitcnt vmcnt(3)" ::: "memory");                       \
    } else {                                                                 \
      asm volatile("s_waitcnt vmcnt(0)" ::: "memory");                       \
    }                                                                        \
    __builtin_amdgcn_s_barrier();                                            \
  }

  int t = 0;
  for (; t < nt - 2; t += 2) {
    GSTEP(t,     afA, bfA, afB, bfB, s1);   // reads frags(t+1) from s1
    GSTEP(t + 1, afB, bfB, afA, bfA, s0);   // reads frags(t+2) from s0
  }
  GSTEP(t, afA, bfA, afB, bfB, s1);         // t == nt-2: reads frags(nt-1)
  __builtin_amdgcn_s_setprio(1);
  mfma16(afB, bfB, acc);
  __builtin_amdgcn_s_setprio(0);
#undef GSTEP

  const long crow = rowA + wm * 64;
  const long ccol = rowB + wn * 64;
  if (OUTF32) {
    float* C = (float*)Cout;
#pragma unroll
    for (int mf = 0; mf < 4; ++mf)
#pragma unroll
      for (int j = 0; j < 4; ++j) {
        long row = crow + mf * 16 + lg * 4 + j;
        float* cp = C + row * N + ccol + lr;
#pragma unroll
        for (int nf = 0; nf < 4; ++nf) cp[nf * 16] = acc[mf][nf][j];
      }
  } else {
    unsigned short* C = (unsigned short*)Cout;
#pragma unroll
    for (int mf = 0; mf < 4; ++mf)
#pragma unroll
      for (int j = 0; j < 4; ++j) {
        long row = crow + mf * 16 + lg * 4 + j;
        unsigned short* cp = C + row * N + ccol + lr;
#pragma unroll
        for (int nf = 0; nf < 4; ++nf) cp[nf * 16] = f2bf(acc[mf][nf][j]);
      }
  }
}

// In-place RoPE on bf16 qkv buffer (q heads 0..31, k heads 32..39).
__global__ __launch_bounds__(256) void rope_kernel(unsigned int* __restrict__ qkv32,
                                                   const float* __restrict__ cosb,
                                                   const float* __restrict__ sinb) {
  int t = blockIdx.x * 256 + threadIdx.x;
  int i  = t & 63;
  int sh = t >> 6;
  int hh = sh % 40;
  int s  = sh / 40;
  int col2 = (hh < 32) ? (hh * 64 + i) : (2048 + (hh - 32) * 64 + i);
  unsigned int* p = qkv32 + (long)s * (QKVN / 2) + col2;
  unsigned int v = *p;
  float tr = __builtin_bit_cast(float, (v & 0xffffu) << 16);
  float ti = __builtin_bit_cast(float, v & 0xffff0000u);
  float c  = cosb[s * 64 + i];
  float sn = sinb[s * 64 + i];
  float orr = tr * c - ti * sn;
  float oi  = tr * sn + ti * c;
  *p = (unsigned int)f2bf(orr) | ((unsigned int)f2bf(oi) << 16);
}

// V transpose: vT[kh][hd][s] from qkv[s][5120 + kh*128 + hd].
__global__ __launch_bounds__(256) void vtrans_kernel(const bf16_t* __restrict__ qkv,
                                                     bf16_t* __restrict__ vT) {
  const int kh = blockIdx.x;
  const int hd = threadIdx.x & 127;
  const int s0 = blockIdx.y * 16 + (threadIdx.x >> 7) * 8;
  u16x8 v;
#pragma unroll
  for (int e = 0; e < 8; ++e)
    v[e] = *(const unsigned short*)(qkv + (long)(s0 + e) * QKVN + 5120 + kh * HDIM + hd);
  *(u16x8*)(vT + ((long)kh * HDIM + hd) * S_LEN + s0) = v;
}

// Flash attention: block = (64 q-rows, 1 head), 4 waves x 16 q-rows, KVBLK=64.
__global__ __launch_bounds__(256) void attn_kernel(const bf16_t* __restrict__ qkv,
                                                   const bf16_t* __restrict__ vT,
                                                   unsigned short* __restrict__ ob) {
  __shared__ bf16_t Kt[64 * 128];
  __shared__ bf16_t Vt[128 * 64];
  __shared__ bf16_t Pl[4 * 16 * 64];
  const int h  = blockIdx.x;
  const int qi = 31 - blockIdx.y;
  const int qb = qi * 64;
  const int kh = h >> 2;
  const int tid = threadIdx.x, lane = tid & 63, w = tid >> 6;
  const int lg = lane >> 4, lr = lane & 15;
  const int qrow0 = qb + w * 16;

  bf16x8 qf[4];
  const bf16_t* qptr = qkv + (long)(qrow0 + lr) * QKVN + h * HDIM + lg * 8;
#pragma unroll
  for (int kk = 0; kk < 4; ++kk) qf[kk] = *(const bf16x8*)(qptr + kk * 32);

  const f32x4 z4 = {0.f, 0.f, 0.f, 0.f};
  f32x4 oacc[8];
#pragma unroll
  for (int c = 0; c < 8; ++c) oacc[c] = z4;
  float m[4]    = {-1e30f, -1e30f, -1e30f, -1e30f};
  float lsum[4] = {0.f, 0.f, 0.f, 0.f};

  char* KtB = (char*)Kt;
  char* VtB = (char*)Vt;
  char* PlB = (char*)Pl + w * 2048;
  const float scale = 0.08838834764831845f;
  const int ntiles = qi + 1;

  for (int t = 0; t < ntiles; ++t) {
    const int kv0 = t * 64;
    __syncthreads();
#pragma unroll
    for (int it = 0; it < 4; ++it) {
      int cch = tid + it * 256;
      int r = cch >> 4, c = cch & 15;
      const bf16_t* src = qkv + (long)(kv0 + r) * QKVN + 4096 + kh * HDIM
                          + ((c ^ (r & 7)) * 8);
      gload_lds16(src, KtB + cch * 16);
    }
#pragma unroll
    for (int it = 0; it < 4; ++it) {
      int cch = tid + it * 256;
      int hd = cch >> 3, c = cch & 7;
      const bf16_t* src = vT + ((long)kh * HDIM + hd) * S_LEN + kv0
                          + ((c ^ (hd & 7)) * 8);
      gload_lds16(src, VtB + cch * 16);
    }
    __syncthreads();

    f32x4 sf[4];
#pragma unroll
    for (int f = 0; f < 4; ++f) {
      f32x4 a = z4;
      int n = f * 16 + lr;
      int rb = n * 256, sw = (n & 7) << 4;
#pragma unroll
      for (int kk = 0; kk < 4; ++kk) {
        bf16x8 kf = *(const bf16x8*)(KtB + rb + (((kk * 4 + lg) * 16) ^ sw));
        a = __builtin_amdgcn_mfma_f32_16x16x32_bf16(qf[kk], kf, a, 0, 0, 0);
      }
      sf[f] = a;
    }

    float sc_arr[4];
#pragma unroll
    for (int j = 0; j < 4; ++j) {
      int qrow = qrow0 + lg * 4 + j;
      float sv[4];
#pragma unroll
      for (int f = 0; f < 4; ++f) {
        float s = sf[f][j] * scale;
        if (kv0 + f * 16 + lr > qrow) s = -1e9f;
        sv[f] = s;
      }
      float mx = fmaxf(fmaxf(sv[0], sv[1]), fmaxf(sv[2], sv[3]));
      mx = fmaxf(mx, __shfl_xor(mx, 1));
      mx = fmaxf(mx, __shfl_xor(mx, 2));
      mx = fmaxf(mx, __shfl_xor(mx, 4));
      mx = fmaxf(mx, __shfl_xor(mx, 8));
      float mn = fmaxf(m[j], mx);
      float p[4];
#pragma unroll
      for (int f = 0; f < 4; ++f) p[f] = __expf(sv[f] - mn);
      float ps = (p[0] + p[1]) + (p[2] + p[3]);
      ps += __shfl_xor(ps, 1);
      ps += __shfl_xor(ps, 2);
      ps += __shfl_xor(ps, 4);
      ps += __shfl_xor(ps, 8);
      float sc = __expf(m[j] - mn);
      lsum[j] = lsum[j] * sc + ps;
      m[j] = mn;
      sc_arr[j] = sc;
      int row = lg * 4 + j;
      int swp = (row & 7) << 4;
#pragma unroll
      for (int f = 0; f < 4; ++f)
        *(unsigned short*)(PlB + row * 128 + (((f * 16 + lr) * 2) ^ swp)) = f2bf(p[f]);
    }
#pragma unroll
    for (int c = 0; c < 8; ++c)
#pragma unroll
      for (int j = 0; j < 4; ++j) oacc[c][j] *= sc_arr[j];

    bf16x8 pfr[2];
#pragma unroll
    for (int kk = 0; kk < 2; ++kk)
      pfr[kk] = *(const bf16x8*)(PlB + lr * 128 + (((kk * 4 + lg) * 16) ^ ((lr & 7) << 4)));
#pragma unroll
    for (int c = 0; c < 8; ++c) {
      int hd = c * 16 + lr;
      int rb = hd * 128, sw = (hd & 7) << 4;
#pragma unroll
      for (int kk = 0; kk < 2; ++kk) {
        bf16x8 vf = *(const bf16x8*)(VtB + rb + (((kk * 4 + lg) * 16) ^ sw));
        oacc[c] = __builtin_amdgcn_mfma_f32_16x16x32_bf16(pfr[kk], vf, oacc[c], 0, 0, 0);
      }
    }
  }

  float rl[4];
#pragma unroll
  for (int j = 0; j < 4; ++j) rl[j] = 1.f / lsum[j];
#pragma unroll
  for (int c = 0; c < 8; ++c)
#pragma unroll
    for (int j = 0; j < 4; ++j) {
      long row = qrow0 + lg * 4 + j;
      ob[row * 4096 + h * 128 + c * 16 + lr] = f2bf(oacc[c][j] * rl[j]);
    }
}

extern "C" void kernel_launch(void* const* d_in, const int* in_sizes, int n_in,
                              void* d_out, int out_size, void* d_ws, size_t ws_size,
                              hipStream_t stream) {
  const float* x  = (const float*)d_in[0];
  const float* wq = (const float*)d_in[1];
  const float* wk = (const float*)d_in[2];
  const float* wv = (const float*)d_in[3];
  const float* wo = (const float*)d_in[4];
  const float* fc = (const float*)d_in[5];
  const float* fs = (const float*)d_in[6];

  char* ws = (char*)d_ws;
  bf16_t* xb    = (bf16_t*)(ws + 0);          // 2048x4096 (dead after gemm1)
  bf16_t* wqkvb = (bf16_t*)(ws + 16777216);   // 6144x4096
  bf16_t* wob   = (bf16_t*)(ws + 67108864);   // 4096x4096
  bf16_t* qkv   = (bf16_t*)(ws + 100663296);  // 2048x6144
  bf16_t* ob    = (bf16_t*)(ws + 125829120);  // 2048x4096
  bf16_t* vT    = (bf16_t*)(ws + 0);          // 8x128x2048 (4 MB, reuses xb)

  cvt_kernel<<<2048, 256, 0, stream>>>(x,  (unsigned short*)xb,                    (2048 * 4096) / 4);
  cvt_kernel<<<2048, 256, 0, stream>>>(wq, (unsigned short*)wqkvb,                 (4096 * 4096) / 4);
  cvt_kernel<<<1024, 256, 0, stream>>>(wk, (unsigned short*)(wqkvb + 4096 * 4096), (1024 * 4096) / 4);
  cvt_kernel<<<1024, 256, 0, stream>>>(wv, (unsigned short*)(wqkvb + 5120 * 4096), (1024 * 4096) / 4);
  cvt_kernel<<<2048, 256, 0, stream>>>(wo, (unsigned short*)wob,                   (4096 * 4096) / 4);

  gemm_pipe<0><<<384, 512, 0, stream>>>(xb, wqkvb, qkv, 2048, 6144, 4096, 48);
  vtrans_kernel<<<dim3(8, 128), 256, 0, stream>>>(qkv, vT);
  rope_kernel<<<20480, 256, 0, stream>>>((unsigned int*)qkv, fc, fs);
  attn_kernel<<<dim3(32, 32), 256, 0, stream>>>(qkv, vT, (unsigned short*)ob);
  gemm_pipe<1><<<256, 512, 0, stream>>>(ob, wob, d_out, 2048, 4096, 4096, 32);
}

// Round 7
// 365.996 us; speedup vs baseline: 1.0450x; 1.0450x over previous
//
#include <hip/hip_runtime.h>
#include <hip/hip_bf16.h>
#include <stdint.h>

typedef __bf16 bf16_t;
typedef __attribute__((ext_vector_type(8))) __bf16 bf16x8;
typedef __attribute__((ext_vector_type(4))) float f32x4;
typedef __attribute__((ext_vector_type(8))) unsigned short u16x8;

#define S_LEN 2048
#define DIM   4096
#define QKVN  6144
#define NHEAD 32
#define HDIM  128

typedef __attribute__((address_space(1))) unsigned int as1_u32;
typedef __attribute__((address_space(3))) unsigned int as3_u32;

__device__ __forceinline__ unsigned short f2bf(float f) {
  unsigned u = __builtin_bit_cast(unsigned, f);
  u += 0x7fffu + ((u >> 16) & 1u);
  return (unsigned short)(u >> 16);
}

__device__ __forceinline__ void gload_lds16(const void* g, void* l) {
  __builtin_amdgcn_global_load_lds(
      (as1_u32*)(unsigned long long)(uintptr_t)g,
      (as3_u32*)(unsigned int)(uintptr_t)l,
      16, 0, 0);
}

__global__ __launch_bounds__(256) void cvt_kernel(const float* __restrict__ in,
                                                  unsigned short* __restrict__ out,
                                                  int n4) {
  int idx = blockIdx.x * 256 + threadIdx.x;
  int stride = gridDim.x * 256;
  for (int i = idx; i < n4; i += stride) {
    float4 v = ((const float4*)in)[i];
    ushort4 o;
    o.x = f2bf(v.x); o.y = f2bf(v.y); o.z = f2bf(v.z); o.w = f2bf(v.w);
    ((ushort4*)out)[i] = o;
  }
}

// ------ 256x128 pipelined GEMM, BK=32, 8 waves (4M x 2N), 512 threads -----
// C(M,N) = A(M,K) * B(N,K)^T. LDS = 3 slots x (A 256x32 + B 128x32) = 72KB.
// Depth-2 ledger: body(t) = { ds_read frags(t+1) | MFMA(t) overlaps; lgkm(0);
// barrier; stage(t+4)->slot(t+1); vmcnt(6) [tile t+2 landed -- issued TWO
// bodies ago; t+3,t+4 in flight]; barrier }. Issue->wait distance = 2 steps
// (R6's was 1 step => ~700cyc exposed HBM latency per step).
// Swizzle key (row>>1)&3 both sides (R4-verified: conflicts = 0).
__device__ __forceinline__ bf16x8 frag_ld(const char* base, int row, int lg) {
  return *(const bf16x8*)(base + row * 64 + ((lg ^ ((row >> 1) & 3)) << 4));
}

__device__ __forceinline__ void load_frags(const char* slot, int wm, int wn,
                                           int lg, int lr, bf16x8* af, bf16x8* bf) {
#pragma unroll
  for (int i = 0; i < 4; ++i) af[i] = frag_ld(slot, wm * 64 + i * 16 + lr, lg);
#pragma unroll
  for (int i = 0; i < 4; ++i)
    bf[i] = frag_ld(slot + 16384, wn * 64 + i * 16 + lr, lg);
}

// 3 loads/thread: A rows tid>>2 and 128+(tid>>2), B row tid>>2.
__device__ __forceinline__ void stage_slot(const bf16_t* a0, const bf16_t* b0,
                                           long ldk128, int k0, char* slot, int tid) {
  gload_lds16(a0 + k0,          slot + tid * 16);
  gload_lds16(a0 + ldk128 + k0, slot + 8192 + tid * 16);
  gload_lds16(b0 + k0,          slot + 16384 + tid * 16);
}

__device__ __forceinline__ void mfma16(const bf16x8* af, const bf16x8* bf,
                                       f32x4 (*acc)[4]) {
#pragma unroll
  for (int mf = 0; mf < 4; ++mf)
#pragma unroll
    for (int nf = 0; nf < 4; ++nf)
      acc[mf][nf] = __builtin_amdgcn_mfma_f32_16x16x32_bf16(af[mf], bf[nf],
                                                            acc[mf][nf], 0, 0, 0);
}

template <int OUTF32>
__global__ __launch_bounds__(512, 2) void gemm_pipe(const bf16_t* __restrict__ A,
                                                    const bf16_t* __restrict__ B,
                                                    void* __restrict__ Cout,
                                                    int M, int N, int K, int nxt) {
  __shared__ char lds[73728];
  const int tid = threadIdx.x;
  const int lane = tid & 63, w = tid >> 6;
  const int wm = w >> 1, wn = w & 1;     // 4 M-waves x 2 N-waves, 64x64 each
  const int lg = lane >> 4, lr = lane & 15;
  const int nwg = gridDim.x;
  const int orig = blockIdx.x;
  const int wgid = (orig & 7) * (nwg >> 3) + (orig >> 3);  // nwg % 8 == 0
  const int bx = wgid % nxt, by = wgid / nxt;
  const long rowA = (long)by * 256;
  const long rowB = (long)bx * 128;

  f32x4 acc[4][4];
  const f32x4 z4 = {0.f, 0.f, 0.f, 0.f};
#pragma unroll
  for (int i = 0; i < 4; ++i)
#pragma unroll
    for (int j = 0; j < 4; ++j) acc[i][j] = z4;

  const int srow = tid >> 2, s4 = tid & 3;
  const long ldk128 = (long)128 * K;
  const bf16_t* Asrc = A + (rowA + srow) * (long)K + ((s4 ^ ((srow >> 1) & 3)) << 3);
  const bf16_t* Bsrc = B + (rowB + srow) * (long)K + ((s4 ^ ((srow >> 1) & 3)) << 3);

  char* c0 = lds;            // slot(t)   at loop entry
  char* c1 = lds + 24576;    // slot(t+1)
  char* c2 = lds + 49152;    // slot(t+2)
  const int nt = K >> 5;     // 128 for both GEMMs; even, >= 8

  bf16x8 afA[4], bfA[4], afB[4], bfB[4];

  // prologue: stage 0,1,2; read frags(0); stage 3 -> slot0; tile1 landed.
  stage_slot(Asrc, Bsrc, ldk128, 0,  c0, tid);
  stage_slot(Asrc, Bsrc, ldk128, 32, c1, tid);
  stage_slot(Asrc, Bsrc, ldk128, 64, c2, tid);
  asm volatile("s_waitcnt vmcnt(6)" ::: "memory");   // tile0 landed
  __builtin_amdgcn_s_barrier();
  load_frags(c0, wm, wn, lg, lr, afA, bfA);
  asm volatile("s_waitcnt lgkmcnt(0)" ::: "memory");
  __builtin_amdgcn_sched_barrier(0);
  __builtin_amdgcn_s_barrier();                      // all waves read tile0
  stage_slot(Asrc, Bsrc, ldk128, 96, c0, tid);       // tile3 -> slot0
  asm volatile("s_waitcnt vmcnt(6)" ::: "memory");   // tile1 landed
  __builtin_amdgcn_s_barrier();
  // body(0) entry: frags(0) in regs; tile1 landed; t2,t3 in flight (6).

#define GBODY(afC, bfC, afN, bfN, SLOT, DOSTAGE, STT, WAITLINE)              \
  {                                                                          \
    load_frags(SLOT, wm, wn, lg, lr, afN, bfN);                              \
    __builtin_amdgcn_sched_barrier(0);                                       \
    __builtin_amdgcn_s_setprio(1);                                           \
    mfma16(afC, bfC, acc);                                                   \
    __builtin_amdgcn_s_setprio(0);                                           \
    asm volatile("s_waitcnt lgkmcnt(0)" ::: "memory");                       \
    __builtin_amdgcn_sched_barrier(0);                                       \
    __builtin_amdgcn_s_barrier();                                            \
    if (DOSTAGE) stage_slot(Asrc, Bsrc, ldk128, (STT) * 32, SLOT, tid);      \
    asm volatile(WAITLINE ::: "memory");                                     \
    __builtin_amdgcn_s_barrier();                                            \
  }

  int t = 0;
  for (; t + 6 <= nt; t += 2) {
    GBODY(afA, bfA, afB, bfB, c1, 1, t + 4, "s_waitcnt vmcnt(6)");
    GBODY(afB, bfB, afA, bfA, c2, 1, t + 5, "s_waitcnt vmcnt(6)");
    char* tmp = c2; c2 = c1; c1 = c0; c0 = tmp;  // (c0,c1,c2) <- (c2,c0,c1)
  }
  // tail: t == nt-4. bodies nt-4..nt-2, then bare MFMA(nt-1).
  GBODY(afA, bfA, afB, bfB, c1, 0, 0, "s_waitcnt vmcnt(3)");
  GBODY(afB, bfB, afA, bfA, c2, 0, 0, "s_waitcnt vmcnt(0)");
  GBODY(afA, bfA, afB, bfB, c0, 0, 0, "s_waitcnt vmcnt(0)");
  __builtin_amdgcn_s_setprio(1);
  mfma16(afB, bfB, acc);
  __builtin_amdgcn_s_setprio(0);
#undef GBODY

  const long crow = rowA + wm * 64;
  const long ccol = rowB + wn * 64;
  if (OUTF32) {
    float* C = (float*)Cout;
#pragma unroll
    for (int mf = 0; mf < 4; ++mf)
#pragma unroll
      for (int j = 0; j < 4; ++j) {
        long row = crow + mf * 16 + lg * 4 + j;
        float* cp = C + row * N + ccol + lr;
#pragma unroll
        for (int nf = 0; nf < 4; ++nf) cp[nf * 16] = acc[mf][nf][j];
      }
  } else {
    unsigned short* C = (unsigned short*)Cout;
#pragma unroll
    for (int mf = 0; mf < 4; ++mf)
#pragma unroll
      for (int j = 0; j < 4; ++j) {
        long row = crow + mf * 16 + lg * 4 + j;
        unsigned short* cp = C + row * N + ccol + lr;
#pragma unroll
        for (int nf = 0; nf < 4; ++nf) cp[nf * 16] = f2bf(acc[mf][nf][j]);
      }
  }
}

// In-place RoPE on bf16 qkv buffer (q heads 0..31, k heads 32..39).
__global__ __launch_bounds__(256) void rope_kernel(unsigned int* __restrict__ qkv32,
                                                   const float* __restrict__ cosb,
                                                   const float* __restrict__ sinb) {
  int t = blockIdx.x * 256 + threadIdx.x;
  int i  = t & 63;
  int sh = t >> 6;
  int hh = sh % 40;
  int s  = sh / 40;
  int col2 = (hh < 32) ? (hh * 64 + i) : (2048 + (hh - 32) * 64 + i);
  unsigned int* p = qkv32 + (long)s * (QKVN / 2) + col2;
  unsigned int v = *p;
  float tr = __builtin_bit_cast(float, (v & 0xffffu) << 16);
  float ti = __builtin_bit_cast(float, v & 0xffff0000u);
  float c  = cosb[s * 64 + i];
  float sn = sinb[s * 64 + i];
  float orr = tr * c - ti * sn;
  float oi  = tr * sn + ti * c;
  *p = (unsigned int)f2bf(orr) | ((unsigned int)f2bf(oi) << 16);
}

// V transpose: vT[kh][hd][s] from qkv[s][5120 + kh*128 + hd].
__global__ __launch_bounds__(256) void vtrans_kernel(const bf16_t* __restrict__ qkv,
                                                     bf16_t* __restrict__ vT) {
  const int kh = blockIdx.x;
  const int hd = threadIdx.x & 127;
  const int s0 = blockIdx.y * 16 + (threadIdx.x >> 7) * 8;
  u16x8 v;
#pragma unroll
  for (int e = 0; e < 8; ++e)
    v[e] = *(const unsigned short*)(qkv + (long)(s0 + e) * QKVN + 5120 + kh * HDIM + hd);
  *(u16x8*)(vT + ((long)kh * HDIM + hd) * S_LEN + s0) = v;
}

// Flash attention: block = (64 q-rows, 1 head), 4 waves x 16 q-rows, KVBLK=64.
__global__ __launch_bounds__(256) void attn_kernel(const bf16_t* __restrict__ qkv,
                                                   const bf16_t* __restrict__ vT,
                                                   unsigned short* __restrict__ ob) {
  __shared__ bf16_t Kt[64 * 128];
  __shared__ bf16_t Vt[128 * 64];
  __shared__ bf16_t Pl[4 * 16 * 64];
  const int h  = blockIdx.x;
  const int qi = 31 - blockIdx.y;
  const int qb = qi * 64;
  const int kh = h >> 2;
  const int tid = threadIdx.x, lane = tid & 63, w = tid >> 6;
  const int lg = lane >> 4, lr = lane & 15;
  const int qrow0 = qb + w * 16;

  bf16x8 qf[4];
  const bf16_t* qptr = qkv + (long)(qrow0 + lr) * QKVN + h * HDIM + lg * 8;
#pragma unroll
  for (int kk = 0; kk < 4; ++kk) qf[kk] = *(const bf16x8*)(qptr + kk * 32);

  const f32x4 z4 = {0.f, 0.f, 0.f, 0.f};
  f32x4 oacc[8];
#pragma unroll
  for (int c = 0; c < 8; ++c) oacc[c] = z4;
  float m[4]    = {-1e30f, -1e30f, -1e30f, -1e30f};
  float lsum[4] = {0.f, 0.f, 0.f, 0.f};

  char* KtB = (char*)Kt;
  char* VtB = (char*)Vt;
  char* PlB = (char*)Pl + w * 2048;
  const float scale = 0.08838834764831845f;
  const int ntiles = qi + 1;

  for (int t = 0; t < ntiles; ++t) {
    const int kv0 = t * 64;
    __syncthreads();
#pragma unroll
    for (int it = 0; it < 4; ++it) {
      int cch = tid + it * 256;
      int r = cch >> 4, c = cch & 15;
      const bf16_t* src = qkv + (long)(kv0 + r) * QKVN + 4096 + kh * HDIM
                          + ((c ^ (r & 7)) * 8);
      gload_lds16(src, KtB + cch * 16);
    }
#pragma unroll
    for (int it = 0; it < 4; ++it) {
      int cch = tid + it * 256;
      int hd = cch >> 3, c = cch & 7;
      const bf16_t* src = vT + ((long)kh * HDIM + hd) * S_LEN + kv0
                          + ((c ^ (hd & 7)) * 8);
      gload_lds16(src, VtB + cch * 16);
    }
    __syncthreads();

    f32x4 sf[4];
#pragma unroll
    for (int f = 0; f < 4; ++f) {
      f32x4 a = z4;
      int n = f * 16 + lr;
      int rb = n * 256, sw = (n & 7) << 4;
#pragma unroll
      for (int kk = 0; kk < 4; ++kk) {
        bf16x8 kf = *(const bf16x8*)(KtB + rb + (((kk * 4 + lg) * 16) ^ sw));
        a = __builtin_amdgcn_mfma_f32_16x16x32_bf16(qf[kk], kf, a, 0, 0, 0);
      }
      sf[f] = a;
    }

    float sc_arr[4];
#pragma unroll
    for (int j = 0; j < 4; ++j) {
      int qrow = qrow0 + lg * 4 + j;
      float sv[4];
#pragma unroll
      for (int f = 0; f < 4; ++f) {
        float s = sf[f][j] * scale;
        if (kv0 + f * 16 + lr > qrow) s = -1e9f;
        sv[f] = s;
      }
      float mx = fmaxf(fmaxf(sv[0], sv[1]), fmaxf(sv[2], sv[3]));
      mx = fmaxf(mx, __shfl_xor(mx, 1));
      mx = fmaxf(mx, __shfl_xor(mx, 2));
      mx = fmaxf(mx, __shfl_xor(mx, 4));
      mx = fmaxf(mx, __shfl_xor(mx, 8));
      float mn = fmaxf(m[j], mx);
      float p[4];
#pragma unroll
      for (int f = 0; f < 4; ++f) p[f] = __expf(sv[f] - mn);
      float ps = (p[0] + p[1]) + (p[2] + p[3]);
      ps += __shfl_xor(ps, 1);
      ps += __shfl_xor(ps, 2);
      ps += __shfl_xor(ps, 4);
      ps += __shfl_xor(ps, 8);
      float sc = __expf(m[j] - mn);
      lsum[j] = lsum[j] * sc + ps;
      m[j] = mn;
      sc_arr[j] = sc;
      int row = lg * 4 + j;
      int swp = (row & 7) << 4;
#pragma unroll
      for (int f = 0; f < 4; ++f)
        *(unsigned short*)(PlB + row * 128 + (((f * 16 + lr) * 2) ^ swp)) = f2bf(p[f]);
    }
#pragma unroll
    for (int c = 0; c < 8; ++c)
#pragma unroll
      for (int j = 0; j < 4; ++j) oacc[c][j] *= sc_arr[j];

    bf16x8 pfr[2];
#pragma unroll
    for (int kk = 0; kk < 2; ++kk)
      pfr[kk] = *(const bf16x8*)(PlB + lr * 128 + (((kk * 4 + lg) * 16) ^ ((lr & 7) << 4)));
#pragma unroll
    for (int c = 0; c < 8; ++c) {
      int hd = c * 16 + lr;
      int rb = hd * 128, sw = (hd & 7) << 4;
#pragma unroll
      for (int kk = 0; kk < 2; ++kk) {
        bf16x8 vf = *(const bf16x8*)(VtB + rb + (((kk * 4 + lg) * 16) ^ sw));
        oacc[c] = __builtin_amdgcn_mfma_f32_16x16x32_bf16(pfr[kk], vf, oacc[c], 0, 0, 0);
      }
    }
  }

  float rl[4];
#pragma unroll
  for (int j = 0; j < 4; ++j) rl[j] = 1.f / lsum[j];
#pragma unroll
  for (int c = 0; c < 8; ++c)
#pragma unroll
    for (int j = 0; j < 4; ++j) {
      long row = qrow0 + lg * 4 + j;
      ob[row * 4096 + h * 128 + c * 16 + lr] = f2bf(oacc[c][j] * rl[j]);
    }
}

extern "C" void kernel_launch(void* const* d_in, const int* in_sizes, int n_in,
                              void* d_out, int out_size, void* d_ws, size_t ws_size,
                              hipStream_t stream) {
  const float* x  = (const float*)d_in[0];
  const float* wq = (const float*)d_in[1];
  const float* wk = (const float*)d_in[2];
  const float* wv = (const float*)d_in[3];
  const float* wo = (const float*)d_in[4];
  const float* fc = (const float*)d_in[5];
  const float* fs = (const float*)d_in[6];

  char* ws = (char*)d_ws;
  bf16_t* xb    = (bf16_t*)(ws + 0);          // 2048x4096 (dead after gemm1)
  bf16_t* wqkvb = (bf16_t*)(ws + 16777216);   // 6144x4096
  bf16_t* wob   = (bf16_t*)(ws + 67108864);   // 4096x4096
  bf16_t* qkv   = (bf16_t*)(ws + 100663296);  // 2048x6144
  bf16_t* ob    = (bf16_t*)(ws + 125829120);  // 2048x4096
  bf16_t* vT    = (bf16_t*)(ws + 0);          // 8x128x2048 (4 MB, reuses xb)

  cvt_kernel<<<2048, 256, 0, stream>>>(x,  (unsigned short*)xb,                    (2048 * 4096) / 4);
  cvt_kernel<<<2048, 256, 0, stream>>>(wq, (unsigned short*)wqkvb,                 (4096 * 4096) / 4);
  cvt_kernel<<<1024, 256, 0, stream>>>(wk, (unsigned short*)(wqkvb + 4096 * 4096), (1024 * 4096) / 4);
  cvt_kernel<<<1024, 256, 0, stream>>>(wv, (unsigned short*)(wqkvb + 5120 * 4096), (1024 * 4096) / 4);
  cvt_kernel<<<2048, 256, 0, stream>>>(wo, (unsigned short*)wob,                   (4096 * 4096) / 4);

  gemm_pipe<0><<<384, 512, 0, stream>>>(xb, wqkvb, qkv, 2048, 6144, 4096, 48);
  vtrans_kernel<<<dim3(8, 128), 256, 0, stream>>>(qkv, vT);
  rope_kernel<<<20480, 256, 0, stream>>>((unsigned int*)qkv, fc, fs);
  attn_kernel<<<dim3(32, 32), 256, 0, stream>>>(qkv, vT, (unsigned short*)ob);
  gemm_pipe<1><<<256, 512, 0, stream>>>(ob, wob, d_out, 2048, 4096, 4096, 32);
}

// Round 8
// 354.380 us; speedup vs baseline: 1.0792x; 1.0328x over previous
//
#include <hip/hip_runtime.h>
#include <hip/hip_bf16.h>
#include <stdint.h>

typedef __bf16 bf16_t;
typedef __attribute__((ext_vector_type(8))) __bf16 bf16x8;
typedef __attribute__((ext_vector_type(4))) float f32x4;
typedef __attribute__((ext_vector_type(8))) unsigned short u16x8;

#define S_LEN 2048
#define DIM   4096
#define QKVN  6144
#define NHEAD 32
#define HDIM  128

typedef __attribute__((address_space(1))) unsigned int as1_u32;
typedef __attribute__((address_space(3))) unsigned int as3_u32;

__device__ __forceinline__ unsigned short f2bf(float f) {
  unsigned u = __builtin_bit_cast(unsigned, f);
  u += 0x7fffu + ((u >> 16) & 1u);
  return (unsigned short)(u >> 16);
}

__device__ __forceinline__ void gload_lds16(const void* g, void* l) {
  __builtin_amdgcn_global_load_lds(
      (as1_u32*)(unsigned long long)(uintptr_t)g,
      (as3_u32*)(unsigned int)(uintptr_t)l,
      16, 0, 0);
}

// Fused f32->bf16 conversion for all 5 inputs (one launch, grid-stride).
__global__ __launch_bounds__(256) void cvt5_kernel(const float* __restrict__ x,
                                                   const float* __restrict__ wq,
                                                   const float* __restrict__ wk,
                                                   const float* __restrict__ wv,
                                                   const float* __restrict__ wo,
                                                   ushort4* __restrict__ xb,
                                                   ushort4* __restrict__ wqkvb,
                                                   ushort4* __restrict__ wob) {
  const long N0 = 2097152;           // x  : 2048*4096/4
  const long N1 = N0 + 4194304;      // wq : 4096*4096/4
  const long N2 = N1 + 1048576;      // wk
  const long N3 = N2 + 1048576;      // wv
  const long N4 = N3 + 4194304;      // wo
  long idx = (long)blockIdx.x * 256 + threadIdx.x;
  long stride = (long)gridDim.x * 256;
  for (long i = idx; i < N4; i += stride) {
    const float4* s; ushort4* d; long o;
    if (i < N0)      { s = (const float4*)x;  d = xb;              o = i; }
    else if (i < N1) { s = (const float4*)wq; d = wqkvb;           o = i - N0; }
    else if (i < N2) { s = (const float4*)wk; d = wqkvb + 4194304; o = i - N1; }
    else if (i < N3) { s = (const float4*)wv; d = wqkvb + 5242880; o = i - N2; }
    else             { s = (const float4*)wo; d = wob;             o = i - N3; }
    float4 v = s[o];
    ushort4 r;
    r.x = f2bf(v.x); r.y = f2bf(v.y); r.z = f2bf(v.z); r.w = f2bf(v.w);
    d[o] = r;
  }
}

// ------ 256x128 GEMM, BK=32, 8 waves (4M x 2N), 512 threads (R4-exact) ----
// C(M,N) = A(M,K) * B(N,K)^T. LDS 48KB: 2 buffers x (A 256x32 + B 128x32).
// Swizzle key (row>>1)&3 both sides: ds_read_b128 conflict-free (R4: 0).
// Counted vmcnt(3): staging loads span barriers; best measured structure
// (R4 125us QKV) -- R5/R6/R7 deeper pipelines all regressed vs this.
__device__ __forceinline__ void stage_A(const bf16_t* __restrict__ g, int ldk,
                                        long rowBase, int k0, char* ldsBase, int tid) {
#pragma unroll
  for (int i = 0; i < 2; ++i) {
    int c = tid + i * 512;
    int row = c >> 2, slot = c & 3;
    const bf16_t* src = g + (rowBase + row) * (long)ldk + k0
                        + ((slot ^ ((row >> 1) & 3)) << 3);
    gload_lds16(src, ldsBase + c * 16);
  }
}

__device__ __forceinline__ void stage_B(const bf16_t* __restrict__ g, int ldk,
                                        long rowBase, int k0, char* ldsBase, int tid) {
  int row = tid >> 2, slot = tid & 3;
  const bf16_t* src = g + (rowBase + row) * (long)ldk + k0
                      + ((slot ^ ((row >> 1) & 3)) << 3);
  gload_lds16(src, ldsBase + tid * 16);
}

__device__ __forceinline__ bf16x8 frag_ld(const char* base, int row, int lg) {
  return *(const bf16x8*)(base + row * 64 + ((lg ^ ((row >> 1) & 3)) << 4));
}

template <int OUTF32>
__global__ __launch_bounds__(512, 2) void gemm256(const bf16_t* __restrict__ A,
                                                  const bf16_t* __restrict__ B,
                                                  void* __restrict__ Cout,
                                                  int M, int N, int K, int nxt) {
  __shared__ char lds[49152];
  const int tid = threadIdx.x;
  const int lane = tid & 63, w = tid >> 6;
  const int wm = w >> 1, wn = w & 1;     // 4 M-waves x 2 N-waves, 64x64 each
  const int lg = lane >> 4, lr = lane & 15;
  const int nwg = gridDim.x;
  const int orig = blockIdx.x;
  const int wgid = (orig & 7) * (nwg >> 3) + (orig >> 3);  // nwg % 8 == 0
  const int bx = wgid % nxt, by = wgid / nxt;
  const long rowA = (long)by * 256;
  const long rowB = (long)bx * 128;

  f32x4 acc[4][4];
  const f32x4 z4 = {0.f, 0.f, 0.f, 0.f};
#pragma unroll
  for (int i = 0; i < 4; ++i)
#pragma unroll
    for (int j = 0; j < 4; ++j) acc[i][j] = z4;

  // prologue: stage K-tiles 0 and 1 (3 VMEM ops each); wait tile 0 only
  stage_A(A, K, rowA, 0, lds, tid);
  stage_B(B, K, rowB, 0, lds + 16384, tid);
  stage_A(A, K, rowA, 32, lds + 24576, tid);
  stage_B(B, K, rowB, 32, lds + 40960, tid);
  asm volatile("s_waitcnt vmcnt(3)" ::: "memory");
  __builtin_amdgcn_s_barrier();

  const int nt = K >> 5;
  for (int t = 0; t < nt; ++t) {
    char* Ab = lds + (t & 1) * 24576;
    char* Bb = Ab + 16384;
    bf16x8 af[4], bfr[4];
#pragma unroll
    for (int mf = 0; mf < 4; ++mf) af[mf] = frag_ld(Ab, wm * 64 + mf * 16 + lr, lg);
#pragma unroll
    for (int nf = 0; nf < 4; ++nf) bfr[nf] = frag_ld(Bb, wn * 64 + nf * 16 + lr, lg);
    asm volatile("s_waitcnt lgkmcnt(0)" ::: "memory");
    __builtin_amdgcn_sched_barrier(0);
    __builtin_amdgcn_s_barrier();     // all waves' frags in regs; buffers free
    if (t + 2 < nt) {                 // stage t+2 into the buffer just consumed
      stage_A(A, K, rowA, (t + 2) * 32, Ab, tid);
      stage_B(B, K, rowB, (t + 2) * 32, Bb, tid);
    }
    __builtin_amdgcn_s_setprio(1);
#pragma unroll
    for (int mf = 0; mf < 4; ++mf)
#pragma unroll
      for (int nf = 0; nf < 4; ++nf)
        acc[mf][nf] = __builtin_amdgcn_mfma_f32_16x16x32_bf16(af[mf], bfr[nf],
                                                              acc[mf][nf], 0, 0, 0);
    __builtin_amdgcn_s_setprio(0);
    if (t + 2 < nt) {
      asm volatile("s_waitcnt vmcnt(3)" ::: "memory");  // t+1's stage complete
    } else {
      asm volatile("s_waitcnt vmcnt(0)" ::: "memory");
    }
    __builtin_amdgcn_s_barrier();     // next buffer ready for next step's reads
  }

  const long crow = rowA + wm * 64;
  const long ccol = rowB + wn * 64;
  if (OUTF32) {
    float* C = (float*)Cout;
#pragma unroll
    for (int mf = 0; mf < 4; ++mf)
#pragma unroll
      for (int j = 0; j < 4; ++j) {
        long row = crow + mf * 16 + lg * 4 + j;
        float* cp = C + row * N + ccol + lr;
#pragma unroll
        for (int nf = 0; nf < 4; ++nf) cp[nf * 16] = acc[mf][nf][j];
      }
  } else {
    unsigned short* C = (unsigned short*)Cout;
#pragma unroll
    for (int mf = 0; mf < 4; ++mf)
#pragma unroll
      for (int j = 0; j < 4; ++j) {
        long row = crow + mf * 16 + lg * 4 + j;
        unsigned short* cp = C + row * N + ccol + lr;
#pragma unroll
        for (int nf = 0; nf < 4; ++nf) cp[nf * 16] = f2bf(acc[mf][nf][j]);
      }
  }
}

// In-place RoPE on bf16 qkv buffer (q heads 0..31, k heads 32..39).
__global__ __launch_bounds__(256) void rope_kernel(unsigned int* __restrict__ qkv32,
                                                   const float* __restrict__ cosb,
                                                   const float* __restrict__ sinb) {
  int t = blockIdx.x * 256 + threadIdx.x;
  int i  = t & 63;
  int sh = t >> 6;
  int hh = sh % 40;
  int s  = sh / 40;
  int col2 = (hh < 32) ? (hh * 64 + i) : (2048 + (hh - 32) * 64 + i);
  unsigned int* p = qkv32 + (long)s * (QKVN / 2) + col2;
  unsigned int v = *p;
  float tr = __builtin_bit_cast(float, (v & 0xffffu) << 16);
  float ti = __builtin_bit_cast(float, v & 0xffff0000u);
  float c  = cosb[s * 64 + i];
  float sn = sinb[s * 64 + i];
  float orr = tr * c - ti * sn;
  float oi  = tr * sn + ti * c;
  *p = (unsigned int)f2bf(orr) | ((unsigned int)f2bf(oi) << 16);
}

// V transpose: vT[kh][hd][s] from qkv[s][5120 + kh*128 + hd].
__global__ __launch_bounds__(256) void vtrans_kernel(const bf16_t* __restrict__ qkv,
                                                     bf16_t* __restrict__ vT) {
  const int kh = blockIdx.x;
  const int hd = threadIdx.x & 127;
  const int s0 = blockIdx.y * 16 + (threadIdx.x >> 7) * 8;
  u16x8 v;
#pragma unroll
  for (int e = 0; e < 8; ++e)
    v[e] = *(const unsigned short*)(qkv + (long)(s0 + e) * QKVN + 5120 + kh * HDIM + hd);
  *(u16x8*)(vT + ((long)kh * HDIM + hd) * S_LEN + s0) = v;
}

// Flash attention: block = (128 q-rows, 1 head), 8 waves x 16 q-rows, KVBLK=64.
// Each KV tile staged once serves 128 q-rows (2x R7 reuse); lower waves skip
// fully-masked tiles after the staging barriers.
__global__ __launch_bounds__(512) void attn_kernel(const bf16_t* __restrict__ qkv,
                                                   const bf16_t* __restrict__ vT,
                                                   unsigned short* __restrict__ ob) {
  __shared__ bf16_t Kt[64 * 128];     // 16 KB, swizzled
  __shared__ bf16_t Vt[128 * 64];     // 16 KB, swizzled (holds V^T)
  __shared__ bf16_t Pl[8 * 16 * 64];  // 16 KB, per-wave P, swizzled
  const int h  = blockIdx.x;
  const int qi = 15 - (int)blockIdx.y;   // heavy blocks dispatched first
  const int qb = qi * 128;
  const int kh = h >> 2;                 // REPEATS = 4
  const int tid = threadIdx.x, lane = tid & 63, w = tid >> 6;
  const int lg = lane >> 4, lr = lane & 15;
  const int qrow0 = qb + w * 16;

  bf16x8 qf[4];
  const bf16_t* qptr = qkv + (long)(qrow0 + lr) * QKVN + h * HDIM + lg * 8;
#pragma unroll
  for (int kk = 0; kk < 4; ++kk) qf[kk] = *(const bf16x8*)(qptr + kk * 32);

  const f32x4 z4 = {0.f, 0.f, 0.f, 0.f};
  f32x4 oacc[8];
#pragma unroll
  for (int c = 0; c < 8; ++c) oacc[c] = z4;
  float m[4]    = {-1e30f, -1e30f, -1e30f, -1e30f};
  float lsum[4] = {0.f, 0.f, 0.f, 0.f};

  char* KtB = (char*)Kt;
  char* VtB = (char*)Vt;
  char* PlB = (char*)Pl + w * 2048;
  const float scale = 0.08838834764831845f;
  const int ntiles = 2 * qi + 2;
  const int wqmax = qrow0 + 15;

  for (int t = 0; t < ntiles; ++t) {
    const int kv0 = t * 64;
    __syncthreads();
    // K tile: 64 rows x 128 hd = 1024 chunks of 16B; source chunk XOR (r&7).
#pragma unroll
    for (int it = 0; it < 2; ++it) {
      int cch = tid + it * 512;
      int r = cch >> 4, c = cch & 15;
      const bf16_t* src = qkv + (long)(kv0 + r) * QKVN + 4096 + kh * HDIM
                          + ((c ^ (r & 7)) * 8);
      gload_lds16(src, KtB + cch * 16);
    }
    // V^T tile: 128 rows(hd) x 64 kv = 1024 chunks; source chunk XOR (hd&7).
#pragma unroll
    for (int it = 0; it < 2; ++it) {
      int cch = tid + it * 512;
      int hd = cch >> 3, c = cch & 7;
      const bf16_t* src = vT + ((long)kh * HDIM + hd) * S_LEN + kv0
                          + ((c ^ (hd & 7)) * 8);
      gload_lds16(src, VtB + cch * 16);
    }
    __syncthreads();
    if (kv0 > wqmax) continue;  // fully masked for this wave (barriers done)

    // S(16x64) = Q(16x128) * K^T : 4 col-fragments x 4 k-slices
    f32x4 sf[4];
#pragma unroll
    for (int f = 0; f < 4; ++f) {
      f32x4 a = z4;
      int n = f * 16 + lr;
      int rb = n * 256, sw = (n & 7) << 4;
#pragma unroll
      for (int kk = 0; kk < 4; ++kk) {
        bf16x8 kf = *(const bf16x8*)(KtB + rb + (((kk * 4 + lg) * 16) ^ sw));
        a = __builtin_amdgcn_mfma_f32_16x16x32_bf16(qf[kk], kf, a, 0, 0, 0);
      }
      sf[f] = a;
    }

    // online softmax over 64 cols (rows: lg*4+j; cols: f*16+lr)
    float sc_arr[4];
#pragma unroll
    for (int j = 0; j < 4; ++j) {
      int qrow = qrow0 + lg * 4 + j;
      float sv[4];
#pragma unroll
      for (int f = 0; f < 4; ++f) {
        float s = sf[f][j] * scale;
        if (kv0 + f * 16 + lr > qrow) s = -1e9f;
        sv[f] = s;
      }
      float mx = fmaxf(fmaxf(sv[0], sv[1]), fmaxf(sv[2], sv[3]));
      mx = fmaxf(mx, __shfl_xor(mx, 1));
      mx = fmaxf(mx, __shfl_xor(mx, 2));
      mx = fmaxf(mx, __shfl_xor(mx, 4));
      mx = fmaxf(mx, __shfl_xor(mx, 8));
      float mn = fmaxf(m[j], mx);
      float p[4];
#pragma unroll
      for (int f = 0; f < 4; ++f) p[f] = __expf(sv[f] - mn);
      float ps = (p[0] + p[1]) + (p[2] + p[3]);
      ps += __shfl_xor(ps, 1);
      ps += __shfl_xor(ps, 2);
      ps += __shfl_xor(ps, 4);
      ps += __shfl_xor(ps, 8);
      float sc = __expf(m[j] - mn);
      lsum[j] = lsum[j] * sc + ps;
      m[j] = mn;
      sc_arr[j] = sc;
      int row = lg * 4 + j;
      int swp = (row & 7) << 4;
#pragma unroll
      for (int f = 0; f < 4; ++f)
        *(unsigned short*)(PlB + row * 128 + (((f * 16 + lr) * 2) ^ swp)) = f2bf(p[f]);
    }
#pragma unroll
    for (int c = 0; c < 8; ++c)
#pragma unroll
      for (int j = 0; j < 4; ++j) oacc[c][j] *= sc_arr[j];

    // O(16x128) += P(16x64) * V(64x128)
    bf16x8 pfr[2];
#pragma unroll
    for (int kk = 0; kk < 2; ++kk)
      pfr[kk] = *(const bf16x8*)(PlB + lr * 128 + (((kk * 4 + lg) * 16) ^ ((lr & 7) << 4)));
#pragma unroll
    for (int c = 0; c < 8; ++c) {
      int hd = c * 16 + lr;
      int rb = hd * 128, sw = (hd & 7) << 4;
#pragma unroll
      for (int kk = 0; kk < 2; ++kk) {
        bf16x8 vf = *(const bf16x8*)(VtB + rb + (((kk * 4 + lg) * 16) ^ sw));
        oacc[c] = __builtin_amdgcn_mfma_f32_16x16x32_bf16(pfr[kk], vf, oacc[c], 0, 0, 0);
      }
    }
  }

  float rl[4];
#pragma unroll
  for (int j = 0; j < 4; ++j) rl[j] = 1.f / lsum[j];
#pragma unroll
  for (int c = 0; c < 8; ++c)
#pragma unroll
    for (int j = 0; j < 4; ++j) {
      long row = qrow0 + lg * 4 + j;
      ob[row * 4096 + h * 128 + c * 16 + lr] = f2bf(oacc[c][j] * rl[j]);
    }
}

extern "C" void kernel_launch(void* const* d_in, const int* in_sizes, int n_in,
                              void* d_out, int out_size, void* d_ws, size_t ws_size,
                              hipStream_t stream) {
  const float* x  = (const float*)d_in[0];
  const float* wq = (const float*)d_in[1];
  const float* wk = (const float*)d_in[2];
  const float* wv = (const float*)d_in[3];
  const float* wo = (const float*)d_in[4];
  const float* fc = (const float*)d_in[5];
  const float* fs = (const float*)d_in[6];

  char* ws = (char*)d_ws;
  bf16_t* xb    = (bf16_t*)(ws + 0);          // 2048x4096 (dead after gemm1)
  bf16_t* wqkvb = (bf16_t*)(ws + 16777216);   // 6144x4096
  bf16_t* wob   = (bf16_t*)(ws + 67108864);   // 4096x4096
  bf16_t* qkv   = (bf16_t*)(ws + 100663296);  // 2048x6144
  bf16_t* ob    = (bf16_t*)(ws + 125829120);  // 2048x4096
  bf16_t* vT    = (bf16_t*)(ws + 0);          // 8x128x2048 (4 MB, reuses xb)

  cvt5_kernel<<<2048, 256, 0, stream>>>(x, wq, wk, wv, wo,
                                        (ushort4*)xb, (ushort4*)wqkvb, (ushort4*)wob);

  gemm256<0><<<384, 512, 0, stream>>>(xb, wqkvb, qkv, 2048, 6144, 4096, 48);
  vtrans_kernel<<<dim3(8, 128), 256, 0, stream>>>(qkv, vT);
  rope_kernel<<<20480, 256, 0, stream>>>((unsigned int*)qkv, fc, fs);
  attn_kernel<<<dim3(32, 16), 512, 0, stream>>>(qkv, vT, (unsigned short*)ob);
  gemm256<1><<<256, 512, 0, stream>>>(ob, wob, d_out, 2048, 4096, 4096, 32);
}